// Round 2
// baseline (270.157 us; speedup 1.0000x reference)
//
#include <hip/hip_runtime.h>
#include <math.h>

#define B    32
#define CIN  128
#define NN   8192
#define N1   8190   // length after k=3 valid conv
#define CH   10
#define TILE 256

// K1: h2[b][o][t] = relu(b2 + W2 * relu(b1 + conv_k3(signal)))   t in [0,N1)
// 2 outputs per thread, float2 loads, unrolled ci loop for ILP.
__global__ __launch_bounds__(256) void k1_conv12(
    const float* __restrict__ sig, const float* __restrict__ w1, const float* __restrict__ b1,
    const float* __restrict__ w2, const float* __restrict__ b2, float* __restrict__ h2out)
{
    const int p  = blockIdx.x * 256 + threadIdx.x;   // pair index
    const int t2 = 2 * p;                            // first output index
    const int b  = blockIdx.y;
    if (t2 >= N1) return;                            // t2 max valid = 8188 (pair 8188,8189)

    float y0[CH], y1[CH];
#pragma unroll
    for (int o = 0; o < CH; ++o) { y0[o] = b1[o]; y1[o] = b1[o]; }

    const float* sp = sig + (size_t)b * CIN * NN + t2;

#pragma unroll 4
    for (int ci = 0; ci < CIN; ++ci) {
        const float* s = sp + (size_t)ci * NN;
        const float2 lo = *(const float2*)(s);       // s[t2], s[t2+1]   (8B aligned)
        const float2 hi = *(const float2*)(s + 2);   // s[t2+2], s[t2+3] (8B aligned)
        const float* wp = w1 + ci * 3;               // + o*CIN*3 + k
#pragma unroll
        for (int o = 0; o < CH; ++o) {
            const float w0 = wp[o * CIN * 3 + 0];
            const float w1v = wp[o * CIN * 3 + 1];
            const float w2v = wp[o * CIN * 3 + 2];
            y0[o] = fmaf(w0, lo.x, y0[o]);
            y0[o] = fmaf(w1v, lo.y, y0[o]);
            y0[o] = fmaf(w2v, hi.x, y0[o]);
            y1[o] = fmaf(w0, lo.y, y1[o]);
            y1[o] = fmaf(w1v, hi.x, y1[o]);
            y1[o] = fmaf(w2v, hi.y, y1[o]);
        }
    }

#pragma unroll
    for (int o = 0; o < CH; ++o) { y0[o] = fmaxf(y0[o], 0.f); y1[o] = fmaxf(y1[o], 0.f); }

#pragma unroll
    for (int o = 0; o < CH; ++o) {
        float a0 = b2[o], a1 = b2[o];
#pragma unroll
        for (int i = 0; i < CH; ++i) {
            const float w = w2[o * CH + i];
            a0 = fmaf(w, y0[i], a0);
            a1 = fmaf(w, y1[i], a1);
        }
        float2 st; st.x = fmaxf(a0, 0.f); st.y = fmaxf(a1, 0.f);
        *(float2*)(h2out + ((size_t)b * CH + o) * N1 + t2) = st;   // 8B aligned (N1, t2 even)
    }
}

// K2 (fused): per tile, compute lr (convT+relu+1x1 conv+sigmoid) into LDS with
// halo, then the tridiagonal update + log; write unnormalized out + block sums.
__global__ __launch_bounds__(256) void k2_fused(
    const float* __restrict__ h2, const float* __restrict__ cd,
    const float* __restrict__ wt, const float* __restrict__ bt,
    const float* __restrict__ w3, const float* __restrict__ b3,
    const float* __restrict__ cstp, float* __restrict__ outv, float* __restrict__ bsums)
{
    const int b  = blockIdx.y;
    const int t0 = blockIdx.x * TILE;

    __shared__ float lsh[TILE + 4];
    __shared__ float rsh[TILE + 4];

    // lr needed for s in [t0, t0+TILE+2]
    for (int s = t0 + threadIdx.x; s <= t0 + TILE + 2; s += 256) {
        if (s < NN) {
            float acc[CH];
#pragma unroll
            for (int o = 0; o < CH; ++o) acc[o] = bt[o];
#pragma unroll
            for (int i = 0; i < CH; ++i) {
                const float* hp = h2 + ((size_t)b * CH + i) * N1;
                const float v0 = (s < N1)            ? hp[s]     : 0.f;
                const float v1 = (s >= 1 && s <= N1) ? hp[s - 1] : 0.f;
                const float v2 = (s >= 2)            ? hp[s - 2] : 0.f;
                const float* wp = wt + (i * CH) * 3;
#pragma unroll
                for (int o = 0; o < CH; ++o) {
                    acc[o] = fmaf(wp[o * 3 + 0], v0, acc[o]);
                    acc[o] = fmaf(wp[o * 3 + 1], v1, acc[o]);
                    acc[o] = fmaf(wp[o * 3 + 2], v2, acc[o]);
                }
            }
            float l = b3[0], r = b3[1];
#pragma unroll
            for (int o = 0; o < CH; ++o) {
                const float h3 = fmaxf(acc[o], 0.f);
                l = fmaf(w3[o],      h3, l);
                r = fmaf(w3[CH + o], h3, r);
            }
            lsh[s - t0] = 1.f / (1.f + expf(-l));
            rsh[s - t0] = 1.f / (1.f + expf(-r));
        }
    }
    __syncthreads();

    const int t = t0 + threadIdx.x;
    float v = 0.f;
    if (t < N1) {
        const float c0 = cd[(size_t)b * (NN - 1) + t];
        const float c1 = cd[(size_t)b * (NN - 1) + t + 1];
        const float mi = c1 * rsh[threadIdx.x + 1] + c0 * lsh[threadIdx.x + 1];
        const float mo = rsh[threadIdx.x] + lsh[threadIdx.x + 2];
        v = logf(cstp[0] * mi / mo);
        outv[(size_t)b * N1 + t] = v;
    }

    __shared__ float red[256];
    red[threadIdx.x] = v;
    __syncthreads();
#pragma unroll
    for (int s = 128; s > 0; s >>= 1) {
        if (threadIdx.x < s) red[threadIdx.x] += red[threadIdx.x + s];
        __syncthreads();
    }
    if (threadIdx.x == 0) bsums[blockIdx.y * gridDim.x + blockIdx.x] = red[0];
}

// K3: reduce 1024 block sums -> mean
__global__ __launch_bounds__(256) void k3_mean(const float* __restrict__ bsums, float* __restrict__ meanp)
{
    __shared__ float red[256];
    float s = 0.f;
    for (int i = threadIdx.x; i < 1024; i += 256) s += bsums[i];
    red[threadIdx.x] = s;
    __syncthreads();
#pragma unroll
    for (int st = 128; st > 0; st >>= 1) {
        if (threadIdx.x < st) red[threadIdx.x] += red[threadIdx.x + st];
        __syncthreads();
    }
    if (threadIdx.x == 0) meanp[0] = red[0] / (float)(B * N1);
}

// K4: out -= mean
__global__ __launch_bounds__(256) void k4_sub(float* __restrict__ outv, const float* __restrict__ meanp, int n)
{
    const int i = blockIdx.x * 256 + threadIdx.x;
    if (i < n) outv[i] -= meanp[0];
}

extern "C" void kernel_launch(void* const* d_in, const int* in_sizes, int n_in,
                              void* d_out, int out_size, void* d_ws, size_t ws_size,
                              hipStream_t stream)
{
    const float* sig = (const float*)d_in[0];
    const float* cd  = (const float*)d_in[1];
    // d_in[2] = index_diag (always 1 for these shapes)
    const float* w1  = (const float*)d_in[3];
    const float* b1  = (const float*)d_in[4];
    const float* w2  = (const float*)d_in[5];
    const float* b2  = (const float*)d_in[6];
    const float* wt  = (const float*)d_in[7];
    const float* bt  = (const float*)d_in[8];
    const float* w3  = (const float*)d_in[9];
    const float* b3  = (const float*)d_in[10];
    const float* cst = (const float*)d_in[11];

    float* outv = (float*)d_out;

    // workspace layout (floats)
    float* ws   = (float*)d_ws;
    float* h2   = ws;                         // B*CH*N1 = 2,620,800
    float* bsum = h2 + (size_t)B * CH * N1;   // 1024
    float* mean = bsum + 1024;                // 1

    dim3 blk(256);
    dim3 g1((N1 / 2 + 255) / 256, B);         // 16 x 32 = 512 blocks
    dim3 g2((N1 + TILE - 1) / TILE, B);       // 32 x 32 = 1024 blocks

    k1_conv12<<<g1, blk, 0, stream>>>(sig, w1, b1, w2, b2, h2);
    k2_fused <<<g2, blk, 0, stream>>>(h2, cd, wt, bt, w3, b3, cst, outv, bsum);
    k3_mean  <<<dim3(1), blk, 0, stream>>>(bsum, mean);
    k4_sub   <<<dim3((out_size + 255) / 256), blk, 0, stream>>>(outv, mean, out_size);
}

// Round 3
// 255.156 us; speedup vs baseline: 1.0588x; 1.0588x over previous
//
#include <hip/hip_runtime.h>
#include <math.h>

#define B     32
#define CIN   128
#define NN    8192
#define N1    8190     // length after k=3 valid conv
#define N1P   8192     // padded row stride for h2 (16B-aligned float4 rows)
#define CH    10
#define CHUNK 16       // signal channels staged per LDS phase
#define ROWF  260      // floats staged per signal row (256 + 3 halo, rounded to 4)
#define ROWF2 268      // k2 LDS row stride (264 used + pad), 1072B = 16B multiple

// K0: transpose w1[o][ci][k] -> wT[ci][o*3+k] (rows padded to 32 floats)
// so k1's per-channel 30 weights are contiguous -> batched s_load_dwordx16.
__global__ void k0_prep(const float* __restrict__ w1, float* __restrict__ wT)
{
    const int i = blockIdx.x * 256 + threadIdx.x;     // 0..4095
    if (i < CIN * 32) {
        const int ci = i >> 5, r = i & 31;
        float v = 0.f;
        if (r < 30) {
            const int o = r / 3, k = r - o * 3;
            v = w1[(o * CIN + ci) * 3 + k];
        }
        wT[i] = v;
    }
}

// K1: h2[b][o][t] = relu(b2 + W2 * relu(b1 + conv_k3(signal)))
// Cooperative LDS staging, 16-ch chunks, register-prefetch double buffer.
__global__ __launch_bounds__(256, 4) void k1_conv12(
    const float* __restrict__ sig, const float* __restrict__ wT, const float* __restrict__ b1,
    const float* __restrict__ w2, const float* __restrict__ b2, float* __restrict__ h2out)
{
    __shared__ float ls[CHUNK * ROWF];                // 16640 B
    const int tid = threadIdx.x;
    const int b   = blockIdx.y;
    const int t0  = blockIdx.x * 256;
    const float* sb = sig + (size_t)b * CIN * NN;

    float4 pf[5];                                     // prefetch regs (tid<16 uses 5th)

    auto fetch = [&](int c) {
#pragma unroll
        for (int k = 0; k < 5; ++k) {
            const int li = tid + k * 256;             // 0..1039 (+tail)
            if (k == 4 && tid >= 16) break;
            const int row = li / 65, col = li - row * 65;
            const int g = t0 + col * 4;
            const float* p = sb + (size_t)(c * CHUNK + row) * NN + g;
            float4 v = {0.f, 0.f, 0.f, 0.f};
            if (g + 3 < NN) v = *(const float4*)p;    // 16B-aligned (NN%4==0, g%4==0)
            else {                                    // last tile tail only
                if (g + 0 < NN) v.x = p[0];
                if (g + 1 < NN) v.y = p[1];
                if (g + 2 < NN) v.z = p[2];
            }
            pf[k] = v;
        }
    };
    auto store_lds = [&]() {
#pragma unroll
        for (int k = 0; k < 5; ++k) {
            const int li = tid + k * 256;
            if (k == 4 && tid >= 16) break;
            const int row = li / 65, col = li - row * 65;
            *(float4*)&ls[row * ROWF + col * 4] = pf[k];
        }
    };

    float y[CH];
#pragma unroll
    for (int o = 0; o < CH; ++o) y[o] = b1[o];

    fetch(0);
    for (int c = 0; c < CIN / CHUNK; ++c) {
        __syncthreads();
        store_lds();
        __syncthreads();
        if (c < CIN / CHUNK - 1) fetch(c + 1);        // loads in flight during compute

        const float* wbase = wT + c * CHUNK * 32;
#pragma unroll
        for (int cl = 0; cl < CHUNK; ++cl) {
            const float s0 = ls[cl * ROWF + tid + 0];
            const float s1 = ls[cl * ROWF + tid + 1];
            const float s2 = ls[cl * ROWF + tid + 2];
            const float* wrow = wbase + cl * 32;      // 30 contiguous weights
#pragma unroll
            for (int o = 0; o < CH; ++o) {
                y[o] = fmaf(wrow[o * 3 + 0], s0, y[o]);
                y[o] = fmaf(wrow[o * 3 + 1], s1, y[o]);
                y[o] = fmaf(wrow[o * 3 + 2], s2, y[o]);
            }
        }
    }

    const int t = t0 + tid;
    if (t < N1) {
#pragma unroll
        for (int o = 0; o < CH; ++o) y[o] = fmaxf(y[o], 0.f);
#pragma unroll
        for (int o = 0; o < CH; ++o) {
            float a = b2[o];
#pragma unroll
            for (int i = 0; i < CH; ++i) a = fmaf(w2[o * CH + i], y[i], a);
            h2out[((size_t)b * CH + o) * N1P + t] = fmaxf(a, 0.f);
        }
    }
}

// K2: stage h2 tile in LDS; convT(k=3)+relu+1x1+sigmoid -> lsh/rsh in LDS;
// tridiagonal update + log; write unnormalized out + block sums.
__global__ __launch_bounds__(256, 4) void k2_fused(
    const float* __restrict__ h2, const float* __restrict__ cd,
    const float* __restrict__ wt, const float* __restrict__ bt,
    const float* __restrict__ w3, const float* __restrict__ b3,
    const float* __restrict__ cstp, float* __restrict__ outv, float* __restrict__ bsums)
{
    __shared__ float hs[CH * ROWF2];                  // 10720 B
    __shared__ float lsh[260], rsh[260];
    __shared__ float red[256];
    const int tid = threadIdx.x;
    const int b   = blockIdx.y;
    const int t0  = blockIdx.x * 256;
    const float* hb = h2 + (size_t)b * CH * N1P;

    // stage h2[b][row][t0-4 .. t0+259] (zero-filled outside [0,N1))
    for (int li = tid; li < 660; li += 256) {
        const int row = li / 66, col = li - row * 66;
        const int g = t0 - 4 + col * 4;
        const float* p = hb + (size_t)row * N1P + g;
        float4 v = {0.f, 0.f, 0.f, 0.f};
        if (g >= 0 && g + 3 < N1) v = *(const float4*)p;
        else {
            if (g + 0 >= 0 && g + 0 < N1) v.x = p[0];
            if (g + 1 >= 0 && g + 1 < N1) v.y = p[1];
            if (g + 2 >= 0 && g + 2 < N1) v.z = p[2];
            if (g + 3 >= 0 && g + 3 < N1) v.w = p[3];
        }
        *(float4*)&hs[row * ROWF2 + col * 4] = v;
    }
    __syncthreads();

    auto computeLR = [&](int sidx) {                  // s = t0 + sidx
        float acc[CH];
#pragma unroll
        for (int o = 0; o < CH; ++o) acc[o] = bt[o];
#pragma unroll
        for (int i = 0; i < CH; ++i) {
            const float a2 = hs[i * ROWF2 + sidx + 2];   // h2[s-2]
            const float a3 = hs[i * ROWF2 + sidx + 3];   // h2[s-1]
            const float a4 = hs[i * ROWF2 + sidx + 4];   // h2[s]
            const float* wp = wt + i * CH * 3;           // 30 contiguous
#pragma unroll
            for (int o = 0; o < CH; ++o) {
                acc[o] = fmaf(wp[o * 3 + 0], a4, acc[o]);
                acc[o] = fmaf(wp[o * 3 + 1], a3, acc[o]);
                acc[o] = fmaf(wp[o * 3 + 2], a2, acc[o]);
            }
        }
        float l = b3[0], r = b3[1];
#pragma unroll
        for (int o = 0; o < CH; ++o) {
            const float h3 = fmaxf(acc[o], 0.f);
            l = fmaf(w3[o],      h3, l);
            r = fmaf(w3[CH + o], h3, r);
        }
        lsh[sidx] = 1.f / (1.f + __expf(-l));
        rsh[sidx] = 1.f / (1.f + __expf(-r));
    };

    computeLR(tid);
    if (tid < 3) computeLR(256 + tid);                // halo s = t0+256..t0+258
    __syncthreads();

    const int t = t0 + tid;
    float v = 0.f;
    if (t < N1) {
        const float c0 = cd[(size_t)b * (NN - 1) + t];
        const float c1 = cd[(size_t)b * (NN - 1) + t + 1];
        const float mi = c1 * rsh[tid + 1] + c0 * lsh[tid + 1];
        const float mo = rsh[tid] + lsh[tid + 2];
        v = __logf(cstp[0] * mi / mo);
        outv[(size_t)b * N1 + t] = v;
    }

    red[tid] = v;
    __syncthreads();
#pragma unroll
    for (int s = 128; s > 0; s >>= 1) {
        if (tid < s) red[tid] += red[tid + s];
        __syncthreads();
    }
    if (tid == 0) bsums[blockIdx.y * gridDim.x + blockIdx.x] = red[0];
}

// K3: reduce 1024 block sums -> mean
__global__ __launch_bounds__(256) void k3_mean(const float* __restrict__ bsums, float* __restrict__ meanp)
{
    __shared__ float red[256];
    float s = 0.f;
    for (int i = threadIdx.x; i < 1024; i += 256) s += bsums[i];
    red[threadIdx.x] = s;
    __syncthreads();
#pragma unroll
    for (int st = 128; st > 0; st >>= 1) {
        if (threadIdx.x < st) red[threadIdx.x] += red[threadIdx.x + st];
        __syncthreads();
    }
    if (threadIdx.x == 0) meanp[0] = red[0] / (float)(B * N1);
}

// K4: out -= mean
__global__ __launch_bounds__(256) void k4_sub(float* __restrict__ outv, const float* __restrict__ meanp, int n)
{
    const int i = blockIdx.x * 256 + threadIdx.x;
    if (i < n) outv[i] -= meanp[0];
}

extern "C" void kernel_launch(void* const* d_in, const int* in_sizes, int n_in,
                              void* d_out, int out_size, void* d_ws, size_t ws_size,
                              hipStream_t stream)
{
    const float* sig = (const float*)d_in[0];
    const float* cd  = (const float*)d_in[1];
    // d_in[2] = index_diag (1 for these shapes)
    const float* w1  = (const float*)d_in[3];
    const float* b1  = (const float*)d_in[4];
    const float* w2  = (const float*)d_in[5];
    const float* b2  = (const float*)d_in[6];
    const float* wt  = (const float*)d_in[7];
    const float* bt  = (const float*)d_in[8];
    const float* w3  = (const float*)d_in[9];
    const float* b3  = (const float*)d_in[10];
    const float* cst = (const float*)d_in[11];

    float* outv = (float*)d_out;

    // workspace layout (floats)
    float* ws   = (float*)d_ws;
    float* wT   = ws;                          // CIN*32 = 4096
    float* h2   = wT + CIN * 32;               // B*CH*N1P = 2,621,440
    float* bsum = h2 + (size_t)B * CH * N1P;   // 1024
    float* mean = bsum + 1024;                 // 1

    dim3 blk(256);
    dim3 g1(32, B);                            // 32 tiles x 32 batch

    k0_prep  <<<dim3(16), blk, 0, stream>>>(w1, wT);
    k1_conv12<<<g1, blk, 0, stream>>>(sig, wT, b1, w2, b2, h2);
    k2_fused <<<g1, blk, 0, stream>>>(h2, cd, wt, bt, w3, b3, cst, outv, bsum);
    k3_mean  <<<dim3(1), blk, 0, stream>>>(bsum, mean);
    k4_sub   <<<dim3((out_size + 255) / 256), blk, 0, stream>>>(outv, mean, out_size);
}